// Round 1
// baseline (1388.592 us; speedup 1.0000x reference)
//
#include <hip/hip_runtime.h>
#include <hip/hip_bf16.h>

#define S_IMG 1024
#define N_GAUSS_TOTAL 4000000

// Phase 1: per-gaussian scatter with atomicMax on winner index buffer.
__global__ __launch_bounds__(256) void gr_scatter(const float* __restrict__ positions,
                                                  int* __restrict__ winner,
                                                  int n) {
    int i = blockIdx.x * blockDim.x + threadIdx.x;
    if (i >= n) return;
    float px = positions[3 * i + 0];
    float py = positions[3 * i + 1];
    // JAX: ((p + 1.0) * (S/2)).astype(int32) then clip(0, S-1).
    // astype truncates toward zero, same as C cast.
    int x = (int)((px + 1.0f) * (float)(S_IMG / 2));
    int y = (int)((py + 1.0f) * (float)(S_IMG / 2));
    x = min(max(x, 0), S_IMG - 1);
    y = min(max(y, 0), S_IMG - 1);
    atomicMax(&winner[y * S_IMG + x], i);
}

// Phase 2: per-pixel resolve: gather color/opacity of winning gaussian,
// write planar (4, S, S) float32 output.
__global__ __launch_bounds__(256) void gr_resolve(const int* __restrict__ winner,
                                                  const float* __restrict__ colors,
                                                  const float* __restrict__ opacities,
                                                  float* __restrict__ out) {
    int p = blockIdx.x * blockDim.x + threadIdx.x;
    const int SS = S_IMG * S_IMG;
    if (p >= SS) return;
    int w = winner[p];
    float r = 0.f, g = 0.f, b = 0.f, a = 0.f;
    if (w >= 0) {
        float o = opacities[w];
        r = colors[3 * w + 0] * o;
        g = colors[3 * w + 1] * o;
        b = colors[3 * w + 2] * o;
        a = o;
    }
    out[0 * SS + p] = r;
    out[1 * SS + p] = g;
    out[2 * SS + p] = b;
    out[3 * SS + p] = a;
}

extern "C" void kernel_launch(void* const* d_in, const int* in_sizes, int n_in,
                              void* d_out, int out_size, void* d_ws, size_t ws_size,
                              hipStream_t stream) {
    const float* positions = (const float*)d_in[0];   // (N,3)
    const float* colors    = (const float*)d_in[1];   // (N,3)
    const float* opacities = (const float*)d_in[2];   // (N,)
    // d_in[3] camera_params unused by reference; d_in[4] image_size (hardcoded 1024).
    float* out = (float*)d_out;                       // (1,4,S,S) float32
    int*   winner = (int*)d_ws;                       // S*S int32

    const int n = in_sizes[0] / 3;                    // 4,000,000
    const int SS = S_IMG * S_IMG;

    // winner = -1 everywhere (0xFF bytes). Stream memset is graph-capture safe.
    hipMemsetAsync(winner, 0xFF, (size_t)SS * sizeof(int), stream);

    gr_scatter<<<(n + 255) / 256, 256, 0, stream>>>(positions, winner, n);
    gr_resolve<<<(SS + 255) / 256, 256, 0, stream>>>(winner, colors, opacities, out);
}

// Round 2
// 227.741 us; speedup vs baseline: 6.0972x; 6.0972x over previous
//
#include <hip/hip_runtime.h>
#include <hip/hip_bf16.h>

#define S_IMG 1024
#define BORDER_SLOTS 4096     // 1024 top + 1024 bottom + 1022 left + (pad) + 1022 right
#define NB 512                // scatter blocks == number of border scratch slabs
#define NCHUNK 8              // border-reduce parallel chunks over the NB slabs

// Phase 1: grid-stride scatter. Interior pixels -> global atomicMax (low
// contention). Border pixels (where clipping concentrates ~53% of all
// gaussians, ~100k on each corner) -> per-block LDS privatized atomicMax,
// flushed coalesced to a per-block scratch slab.
__global__ __launch_bounds__(256) void gr_scatter(const float* __restrict__ positions,
                                                  int* __restrict__ winner,
                                                  int* __restrict__ border_scratch,
                                                  int n) {
    __shared__ int lds_border[BORDER_SLOTS];
    for (int t = threadIdx.x; t < BORDER_SLOTS; t += 256) lds_border[t] = -1;
    __syncthreads();

    const int stride = gridDim.x * 256;
    for (int i = blockIdx.x * 256 + threadIdx.x; i < n; i += stride) {
        float px = positions[3 * i + 0];
        float py = positions[3 * i + 1];
        // JAX: clip(((p+1)*512).astype(int32), 0, 1023); astype truncates
        // toward zero == C cast.
        int x = (int)((px + 1.0f) * 512.0f);
        int y = (int)((py + 1.0f) * 512.0f);
        x = min(max(x, 0), S_IMG - 1);
        y = min(max(y, 0), S_IMG - 1);
        bool border = (x == 0) || (x == S_IMG - 1) || (y == 0) || (y == S_IMG - 1);
        if (border) {
            int idx;
            if (y == 0)              idx = x;                 // [0,1024)
            else if (y == S_IMG - 1) idx = 1024 + x;          // [1024,2048)
            else if (x == 0)         idx = 2048 + (y - 1);    // [2048,3070)
            else                     idx = 3072 + (y - 1);    // [3072,4094)
            atomicMax(&lds_border[idx], i);
        } else {
            atomicMax(&winner[y * S_IMG + x], i);
        }
    }
    __syncthreads();
    // Coalesced flush of the whole LDS border array (including -1 entries).
    int* dst = border_scratch + (size_t)blockIdx.x * BORDER_SLOTS;
    for (int t = threadIdx.x; t < BORDER_SLOTS; t += 256) dst[t] = lds_border[t];
}

// Phase 1b: reduce the NB per-block border slabs. grid.y chunks each reduce
// NB/NCHUNK slabs then merge with a (now low-contention) global atomicMax.
// Border pixels receive contributions ONLY from this kernel (disjoint from
// the interior direct-atomic set).
__global__ __launch_bounds__(256) void gr_border_reduce(const int* __restrict__ border_scratch,
                                                        int* __restrict__ winner) {
    int p = blockIdx.x * 256 + threadIdx.x;
    if (p >= BORDER_SLOTS) return;
    int b0 = blockIdx.y * (NB / NCHUNK);
    int m = -1;
    #pragma unroll 8
    for (int b = 0; b < NB / NCHUNK; ++b)
        m = max(m, border_scratch[(size_t)(b0 + b) * BORDER_SLOTS + p]);
    if (m < 0) return;          // nothing to contribute (memset left -1)
    int x, y;
    if (p < 1024)      { x = p;        y = 0; }
    else if (p < 2048) { x = p - 1024; y = S_IMG - 1; }
    else if (p < 3072) { int r = p - 2048; if (r > 1021) return; x = 0;         y = r + 1; }
    else               { int r = p - 3072; if (r > 1021) return; x = S_IMG - 1; y = r + 1; }
    atomicMax(&winner[y * S_IMG + x], m);
}

// Phase 2: per-pixel resolve, planar (4,S,S) float32 output.
__global__ __launch_bounds__(256) void gr_resolve(const int* __restrict__ winner,
                                                  const float* __restrict__ colors,
                                                  const float* __restrict__ opacities,
                                                  float* __restrict__ out) {
    int p = blockIdx.x * 256 + threadIdx.x;
    const int SS = S_IMG * S_IMG;
    if (p >= SS) return;
    int w = winner[p];
    float r = 0.f, g = 0.f, b = 0.f, a = 0.f;
    if (w >= 0) {
        float o = opacities[w];
        r = colors[3 * w + 0] * o;
        g = colors[3 * w + 1] * o;
        b = colors[3 * w + 2] * o;
        a = o;
    }
    out[0 * SS + p] = r;
    out[1 * SS + p] = g;
    out[2 * SS + p] = b;
    out[3 * SS + p] = a;
}

extern "C" void kernel_launch(void* const* d_in, const int* in_sizes, int n_in,
                              void* d_out, int out_size, void* d_ws, size_t ws_size,
                              hipStream_t stream) {
    const float* positions = (const float*)d_in[0];   // (N,3)
    const float* colors    = (const float*)d_in[1];   // (N,3)
    const float* opacities = (const float*)d_in[2];   // (N,)
    float* out = (float*)d_out;                       // (1,4,S,S) float32

    const int n  = in_sizes[0] / 3;                   // 4,000,000
    const int SS = S_IMG * S_IMG;

    int* winner         = (int*)d_ws;                           // SS ints (4 MB)
    int* border_scratch = winner + SS;                          // NB*4096 ints (8 MB)

    // winner = -1 everywhere.
    hipMemsetAsync(winner, 0xFF, (size_t)SS * sizeof(int), stream);

    gr_scatter<<<NB, 256, 0, stream>>>(positions, winner, border_scratch, n);

    dim3 grid_br(BORDER_SLOTS / 256, NCHUNK);
    gr_border_reduce<<<grid_br, 256, 0, stream>>>(border_scratch, winner);

    gr_resolve<<<(SS + 255) / 256, 256, 0, stream>>>(winner, colors, opacities, out);
}